// Round 7
// baseline (414.999 us; speedup 1.0000x reference)
//
#include <hip/hip_runtime.h>
#include <hip/hip_bf16.h>
#include <stdint.h>

typedef __attribute__((ext_vector_type(8))) short short8;
typedef __attribute__((ext_vector_type(4))) short short4_t;
typedef __attribute__((ext_vector_type(4))) float f32x4;
typedef __attribute__((ext_vector_type(16))) float f32x16;
typedef __attribute__((ext_vector_type(4))) unsigned uint4v;

#define DEVFN static __device__ __forceinline__

constexpr int BATCH = 16;
constexpr int GRAPH = 1024;
constexpr int IDIM  = 512;
constexpr int EDIM  = 512;
constexpr int NH    = 8;
constexpr int KD    = 64;
constexpr int TOK   = BATCH * GRAPH;   // 16384
constexpr int QKC   = 1024;            // proj row width (Q|K)
constexpr int HC    = 1024;            // heads row width (8 heads * 128)
constexpr float SMSCALE = 0.125f * 1.44269504088896340736f; // 1/sqrt(64) * log2(e)

DEVFN unsigned short f2bf(float x) {
    union { float f; unsigned u; } v; v.f = x;
    unsigned r = v.u + 0x7fffu + ((v.u >> 16) & 1u);
    return (unsigned short)(r >> 16);
}

// packed f32x2 -> bf16x2 (low = a, high = b)
DEVFN unsigned cvtpk(float a, float b) {
    unsigned r;
    asm("v_cvt_pk_bf16_f32 %0, %1, %2" : "=v"(r) : "v"(a), "v"(b));
    return r;
}

// v_permlane32_swap_b32: x' = {x[0:31], y[0:31]}, y' = {x[32:63], y[32:63]}
DEVFN void plswap(unsigned &x, unsigned &y) {
    asm("v_permlane32_swap_b32 %0, %1" : "+v"(x), "+v"(y));
}

DEVFN void load16(const void* g, void* l) {
    __builtin_amdgcn_global_load_lds(
        (const __attribute__((address_space(1))) void*)g,
        (__attribute__((address_space(3))) void*)l, 16, 0, 0);
}

// ---------------- input conversion: fp32 -> bf16 (both streams) -------------
__global__ __launch_bounds__(256) void cvt_x_kernel(const float4* __restrict__ x0,
                                                    const float4* __restrict__ x1,
                                                    short4_t* __restrict__ y0,
                                                    short4_t* __restrict__ y1) {
    const float4* x = blockIdx.y ? x1 : x0;
    short4_t*     y = blockIdx.y ? y1 : y0;
    const int i = blockIdx.x * 256 + threadIdx.x;
    const float4 v = x[i];
    short4_t o;
    o[0] = (short)f2bf(v.x); o[1] = (short)f2bf(v.y);
    o[2] = (short)f2bf(v.z); o[3] = (short)f2bf(v.w);
    y[i] = o;
}

// ---------------- weight packing: LDS-tiled 64x64 transpose -----------------
// qkv dest: [2048][512] bf16 per stream (Q|K|V columns, W_query pre-scaled
// by SMSCALE for the max-free exp2-domain softmax).
// out dest: [512][1024] bf16 per stream.
__global__ __launch_bounds__(256)
void pack_w_kernel(const float* __restrict__ Wqn, const float* __restrict__ Wkn,
                   const float* __restrict__ Wvn,
                   const float* __restrict__ Wqp, const float* __restrict__ Wkp,
                   const float* __restrict__ Wvp,
                   const float* __restrict__ Won, const float* __restrict__ Wop,
                   unsigned short* __restrict__ Wn, unsigned short* __restrict__ Wp2,
                   unsigned short* __restrict__ WoN, unsigned short* __restrict__ WoP)
{
    __shared__ float T[64][65];
    const int bid = blockIdx.x, tid = threadIdx.x;

    const float* src; unsigned short* dst;
    int sld, dld; size_t sbase, dbase;
    float scale = 1.f;

    if (bid < 512) {                       // QKV: 2 streams x 256 tiles
        const int st = bid >> 8, t = bid & 255;
        const int tr = t >> 3, tc = t & 7;
        dst = st ? Wp2 : Wn;
        int head;
        if (tr < 8)       { src = st ? Wqp : Wqn; head = tr;      scale = SMSCALE; }
        else if (tr < 16) { src = st ? Wkp : Wkn; head = tr - 8; }
        else              { src = st ? Wvp : Wvn; head = tr - 16; }
        sld = 64; dld = 512;
        sbase = (size_t)(head * 512 + tc * 64) * 64;
        dbase = (size_t)(tr * 64) * 512 + tc * 64;
    } else {                               // W_out: 2 streams x 128 tiles
        const int b2 = bid - 512;
        const int st = b2 >> 7, t = b2 & 127;
        const int tr = t >> 4, tc = t & 15;
        src = st ? Wop : Won;
        dst = st ? WoP : WoN;
        sld = 512; dld = 1024;
        sbase = (size_t)(tc * 64) * 512 + tr * 64;
        dbase = (size_t)(tr * 64) * 1024 + tc * 64;
    }

    {
        const int j = tid & 63, i0 = tid >> 6;
        #pragma unroll
        for (int p = 0; p < 16; ++p) {
            const int i = p * 4 + i0;
            T[i][j] = src[sbase + (size_t)i * sld + j];
        }
    }
    __syncthreads();
    {
        const int i = tid & 63, j0 = tid >> 6;
        #pragma unroll
        for (int p = 0; p < 16; ++p) {
            const int j = p * 4 + j0;
            dst[dbase + (size_t)j * dld + i] = f2bf(T[i][j] * scale);
        }
    }
}

// ---------------- GEMM: C[M][N] = A[M][K] * Bt[N][K]^T (bf16 MFMA, f32 acc) --
// Grid: (n_blocks, m_blocks, 2) — x = n so XCD (= linear id % 8) pins each
// B panel to one XCD's L2.
// VSPLIT: n0 >= 1024 blocks write bf16 TRANSPOSED into Vt[n-1024][m] (V proj).
// All bf16 epilogues bounce through a padded LDS tile for fully-coalesced
// 256B-row global writes (direct path scattered 8B/2B chunks).
template<int K, bool VSPLIT, typename OutT>
__global__ __launch_bounds__(256)
void gemm_bt_kernel(const unsigned short* __restrict__ A0, const unsigned short* __restrict__ A1,
                    const unsigned short* __restrict__ B0, const unsigned short* __restrict__ B1,
                    OutT* __restrict__ C0, OutT* __restrict__ C1,
                    unsigned short* __restrict__ V0, unsigned short* __restrict__ V1,
                    int ldc)
{
    constexpr int SMEM = VSPLIT ? 128 * 136 : 2 * 128 * 64;
    __shared__ __align__(16) unsigned short smem[SMEM];
    unsigned short* As = smem;          // [128][64]
    unsigned short* Bs = smem + 8192;   // [128][64]

    const unsigned short* A  = blockIdx.z ? A1 : A0;
    const unsigned short* Bt = blockIdx.z ? B1 : B0;

    const int tid = threadIdx.x, wave = tid >> 6, lane = tid & 63;
    const int g = lane >> 4, ln = lane & 15;
    const int n0 = blockIdx.x * 128, m0 = blockIdx.y * 128;
    const int wr = (wave >> 1) * 64, wc = (wave & 1) * 64;

    f32x4 acc[4][4] = {};

    for (int k0 = 0; k0 < K; k0 += 64) {
        #pragma unroll
        for (int j = 0; j < 4; ++j) {
            const int c = (wave * 4 + j) * 64 + lane;      // 0..1023 chunks of 16B
            const int row = c >> 3;
            const int col = ((c & 7) ^ (row & 7)) * 8;
            load16(A  + (size_t)(m0 + row) * K + k0 + col, (char*)As + c * 16);
            load16(Bt + (size_t)(n0 + row) * K + k0 + col, (char*)Bs + c * 16);
        }
        __syncthreads();
        #pragma unroll
        for (int kk = 0; kk < 2; ++kk) {
            short8 af[4], bfr[4];
            #pragma unroll
            for (int i = 0; i < 4; ++i) {
                const int ra = wr + i * 16 + ln;
                af[i]  = *(const short8*)((const char*)As + ra * 128 + (((kk * 4 + g) ^ (ra & 7)) * 16));
                const int rb = wc + i * 16 + ln;
                bfr[i] = *(const short8*)((const char*)Bs + rb * 128 + (((kk * 4 + g) ^ (rb & 7)) * 16));
            }
            #pragma unroll
            for (int mi = 0; mi < 4; ++mi)
                #pragma unroll
                for (int ni = 0; ni < 4; ++ni)
                    acc[mi][ni] = __builtin_amdgcn_mfma_f32_16x16x32_bf16(af[mi], bfr[ni], acc[mi][ni], 0, 0, 0);
        }
        __syncthreads();   // also makes smem safe to reuse in the epilogue
    }

    if constexpr (!VSPLIT) {
        // fp32 direct store (out-GEMM): 4B x 16 consecutive lanes = 64B runs
        OutT* C = blockIdx.z ? C1 : C0;
        #pragma unroll
        for (int mi = 0; mi < 4; ++mi)
            #pragma unroll
            for (int ni = 0; ni < 4; ++ni)
                #pragma unroll
                for (int r = 0; r < 4; ++r) {
                    const size_t m = (size_t)(m0 + wr + mi * 16 + g * 4 + r);
                    const size_t n = (size_t)(n0 + wc + ni * 16 + ln);
                    C[m * ldc + n] = acc[mi][ni][r];
                }
    } else {
        unsigned short* Ts = smem;       // [128][136] padded bounce tile
        if (n0 < 1024) {
            // Q|K: Ts[m][n], then coalesced 256B row writes
            #pragma unroll
            for (int mi = 0; mi < 4; ++mi)
                #pragma unroll
                for (int ni = 0; ni < 4; ++ni) {
                    const int ml = wr + mi * 16 + g * 4;
                    const int nl = wc + ni * 16 + ln;
                    #pragma unroll
                    for (int r = 0; r < 4; ++r)
                        Ts[(ml + r) * 136 + nl] = f2bf(acc[mi][ni][r]);
                }
            __syncthreads();
            unsigned short* C = (unsigned short*)(blockIdx.z ? C1 : C0);
            #pragma unroll
            for (int p = 0; p < 8; ++p) {
                const int c = p * 256 + tid;
                const int row = c >> 4, ch = c & 15;
                *(short8*)(C + (size_t)(m0 + row) * ldc + n0 + ch * 8) =
                    *(const short8*)(Ts + row * 136 + ch * 8);
            }
        } else {
            // V: Ts[n][m] (transpose), then coalesced 256B row writes to Vt
            #pragma unroll
            for (int ni = 0; ni < 4; ++ni) {
                const int nl = wc + ni * 16 + ln;
                #pragma unroll
                for (int mi = 0; mi < 4; ++mi) {
                    const int ml = wr + mi * 16 + g * 4;
                    *(unsigned*)(Ts + nl * 136 + ml)     = cvtpk(acc[mi][ni][0], acc[mi][ni][1]);
                    *(unsigned*)(Ts + nl * 136 + ml + 2) = cvtpk(acc[mi][ni][2], acc[mi][ni][3]);
                }
            }
            __syncthreads();
            unsigned short* Vt = blockIdx.z ? V1 : V0;
            #pragma unroll
            for (int p = 0; p < 8; ++p) {
                const int c = p * 256 + tid;
                const int row = c >> 4, ch = c & 15;
                *(short8*)(Vt + (size_t)(n0 - 1024 + row) * TOK + m0 + ch * 8) =
                    *(const short8*)(Ts + row * 136 + ch * 8);
            }
        }
    }
}

// ---------------- fused flash attention, 32x32x16 MFMA, 64 q per wave -------
// (unchanged from round 6: 124 µs, MfmaUtil 36.5%, HBM 14%)
__global__ __launch_bounds__(256, 2)
void attn_kernel(const unsigned short* __restrict__ projn,
                 const unsigned short* __restrict__ projp,
                 const unsigned short* __restrict__ Vtn,
                 const unsigned short* __restrict__ Vtp,
                 unsigned short* __restrict__ headsn,
                 unsigned short* __restrict__ headsp)
{
    __shared__ unsigned short Kl[2][64 * 64];     // 2 x  8KB  [key][d]
    __shared__ unsigned short Vl[2][128 * 64];    // 2 x 16KB  [v][key]

    const int bid  = blockIdx.x;
    const int slot = bid >> 3;
    const int g    = (bid & 7) * 32 + (slot >> 2);
    const int qt   = slot & 3;
    const int a    = (g & 15) >> 3, h = g & 7;
    const int b    = g >> 4;

    const int tid = threadIdx.x, wave = tid >> 6, lane = tid & 63;
    const int q = lane & 31, hi = lane >> 5;

    const unsigned short* proj = a ? projp : projn;
    const int tok0 = b * GRAPH;
    const size_t qrow0 = (size_t)(tok0 + qt * 256 + wave * 64 + q);  // qi adds 32
    const int qc  = h * KD;
    const int kc  = IDIM + h * KD;
    const int vr0 = (a * NH + h) * KD;

    short8 qf[2][4];
    #pragma unroll
    for (int qi = 0; qi < 2; ++qi)
        #pragma unroll
        for (int ds = 0; ds < 4; ++ds)
            qf[qi][ds] = *(const short8*)(proj + (qrow0 + qi * 32) * QKC + qc + ds * 16 + hi * 8);

    const char* kap[2]; int kds[2];
    #pragma unroll
    for (int j = 0; j < 2; ++j) {
        const int c = (wave * 2 + j) * 64 + lane;
        const int row = c >> 3;
        const int col = ((c & 7) ^ (row & 7)) * 8;
        kap[j] = (const char*)(proj + (size_t)(tok0 + row) * QKC + kc + col);
        kds[j] = c * 16;
    }
    const char* vap[4]; int vds[4];
    #pragma unroll
    for (int j = 0; j < 4; ++j) {
        const int c = (wave * 4 + j) * 64 + lane;
        const int row = c >> 3;
        const int col = ((c & 7) ^ (row & 7)) * 8;
        const unsigned short* base = (row < 64)
            ? (Vtn + (size_t)(vr0 + row) * TOK)
            : (Vtp + (size_t)(vr0 + row - 64) * TOK);
        vap[j] = (const char*)(base + tok0 + col);
        vds[j] = c * 16;
    }

    auto stage = [&](int bb) {
        #pragma unroll
        for (int j = 0; j < 2; ++j) { load16(kap[j], (char*)Kl[bb] + kds[j]); kap[j] += (size_t)64 * QKC * 2; }
        #pragma unroll
        for (int j = 0; j < 4; ++j) { load16(vap[j], (char*)Vl[bb] + vds[j]); vap[j] += 64 * 2; }
    };

    f32x16 oacc[2][4] = {};
    float l_run[2] = {0.f, 0.f};

    stage(0);
    __syncthreads();

    for (int kt = 0; kt < 16; ++kt) {
        const int bb = kt & 1;
        if (kt < 15) stage(bb ^ 1);

        short8 pfrag[2][4];
        #pragma unroll
        for (int kb = 0; kb < 2; ++kb) {
            f32x16 s0 = {}, s1 = {};
            __builtin_amdgcn_s_setprio(1);
            #pragma unroll
            for (int ds = 0; ds < 4; ++ds) {
                const int row = kb * 32 + q;
                const short8 kf = *(const short8*)((const char*)Kl[bb] + row * 128 + (((ds * 2 + hi) ^ (row & 7)) * 16));
                s0 = __builtin_amdgcn_mfma_f32_32x32x16_bf16(kf, qf[0][ds], s0, 0, 0, 0);
                s1 = __builtin_amdgcn_mfma_f32_32x32x16_bf16(kf, qf[1][ds], s1, 0, 0, 0);
            }
            __builtin_amdgcn_s_setprio(0);

            float ps0 = 0.f, ps1 = 0.f;
            #pragma unroll
            for (int r = 0; r < 16; ++r) {
                const float p0 = __builtin_amdgcn_exp2f(s0[r]); s0[r] = p0; ps0 += p0;
                const float p1 = __builtin_amdgcn_exp2f(s1[r]); s1[r] = p1; ps1 += p1;
            }
            l_run[0] += ps0; l_run[1] += ps1;

            #pragma unroll
            for (int sh = 0; sh < 2; ++sh) {
                const int s = kb * 2 + sh, o = 8 * sh;
                {
                    unsigned A0 = cvtpk(s0[o + 0], s0[o + 1]);
                    unsigned A1 = cvtpk(s0[o + 2], s0[o + 3]);
                    unsigned B0 = cvtpk(s0[o + 4], s0[o + 5]);
                    unsigned B1 = cvtpk(s0[o + 6], s0[o + 7]);
                    plswap(A0, B0); plswap(A1, B1);
                    uint4v pw; pw[0] = A0; pw[1] = A1; pw[2] = B0; pw[3] = B1;
                    pfrag[0][s] = __builtin_bit_cast(short8, pw);
                }
                {
                    unsigned A0 = cvtpk(s1[o + 0], s1[o + 1]);
                    unsigned A1 = cvtpk(s1[o + 2], s1[o + 3]);
                    unsigned B0 = cvtpk(s1[o + 4], s1[o + 5]);
                    unsigned B1 = cvtpk(s1[o + 6], s1[o + 7]);
                    plswap(A0, B0); plswap(A1, B1);
                    uint4v pw; pw[0] = A0; pw[1] = A1; pw[2] = B0; pw[3] = B1;
                    pfrag[1][s] = __builtin_bit_cast(short8, pw);
                }
            }
        }

        __builtin_amdgcn_s_setprio(1);
        #pragma unroll
        for (int s = 0; s < 4; ++s) {
            #pragma unroll
            for (int vb = 0; vb < 4; ++vb) {
                const int row = vb * 32 + q;
                const short8 vf = *(const short8*)((const char*)Vl[bb] + row * 128 + (((s * 2 + hi) ^ (row & 7)) * 16));
                oacc[0][vb] = __builtin_amdgcn_mfma_f32_32x32x16_bf16(vf, pfrag[0][s], oacc[0][vb], 0, 0, 0);
                oacc[1][vb] = __builtin_amdgcn_mfma_f32_32x32x16_bf16(vf, pfrag[1][s], oacc[1][vb], 0, 0, 0);
            }
        }
        __builtin_amdgcn_s_setprio(0);
        __syncthreads();
    }

    #pragma unroll
    for (int qi = 0; qi < 2; ++qi) {
        l_run[qi] += __shfl_xor(l_run[qi], 32);
        const float inv = 1.0f / l_run[qi];
        const size_t qrow = qrow0 + qi * 32;
        #pragma unroll
        for (int vb = 0; vb < 4; ++vb) {
            unsigned short* heads = (vb < 2) ? headsn : headsp;
            const int colbase = h * 128 + a * 64 + (vb & 1) * 32;
            #pragma unroll
            for (int w = 0; w < 8; ++w) {
                const unsigned pk = cvtpk(oacc[qi][vb][2 * w] * inv, oacc[qi][vb][2 * w + 1] * inv);
                const int v = ((2 * w) & 3) + 8 * (w >> 1) + 4 * hi;
                *(unsigned*)(heads + qrow * HC + colbase + v) = pk;
            }
        }
    }
}

// ---------------- host launch ----------------
extern "C" void kernel_launch(void* const* d_in, const int* in_sizes, int n_in,
                              void* d_out, int out_size, void* d_ws, size_t ws_size,
                              hipStream_t stream)
{
    const float* hn  = (const float*)d_in[0];
    const float* hp  = (const float*)d_in[1];
    const float* Wqn = (const float*)d_in[2];
    const float* Wqp = (const float*)d_in[3];
    const float* Wkn = (const float*)d_in[4];
    const float* Wkp = (const float*)d_in[5];
    const float* Wvn = (const float*)d_in[6];
    const float* Wvp = (const float*)d_in[7];
    const float* Won = (const float*)d_in[8];
    const float* Wop = (const float*)d_in[9];
    float* out = (float*)d_out;

    char* ws = (char*)d_ws;
    size_t off = 0;
    auto take = [&](size_t nbytes) -> char* {
        char* p = ws + off;
        off += (nbytes + 255) & ~(size_t)255;
        return p;
    };
    unsigned short* Xn  = (unsigned short*)take((size_t)TOK * IDIM * 2);
    unsigned short* Xp  = (unsigned short*)take((size_t)TOK * IDIM * 2);
    unsigned short* Wn  = (unsigned short*)take((size_t)2048 * 512 * 2);
    unsigned short* Wp  = (unsigned short*)take((size_t)2048 * 512 * 2);
    unsigned short* WoN = (unsigned short*)take((size_t)512 * 1024 * 2);
    unsigned short* WoP = (unsigned short*)take((size_t)512 * 1024 * 2);
    unsigned short* Pn  = (unsigned short*)take((size_t)TOK * QKC * 2);
    unsigned short* Pp  = (unsigned short*)take((size_t)TOK * QKC * 2);
    unsigned short* Vtn = (unsigned short*)take((size_t)1024 * TOK * 2);
    unsigned short* Vtp = (unsigned short*)take((size_t)1024 * TOK * 2);
    unsigned short* Hn  = (unsigned short*)take((size_t)TOK * HC * 2);
    unsigned short* Hp  = (unsigned short*)take((size_t)TOK * HC * 2);

    cvt_x_kernel<<<dim3(TOK * IDIM / 4 / 256, 2), 256, 0, stream>>>(
        (const float4*)hn, (const float4*)hp, (short4_t*)Xn, (short4_t*)Xp);
    pack_w_kernel<<<768, 256, 0, stream>>>(
        Wqn, Wkn, Wvn, Wqp, Wkp, Wvp, Won, Wop, Wn, Wp, WoN, WoP);

    // projections: [16384,512] x [512,2048] per stream; grid.x = n-panel (XCD pin)
    gemm_bt_kernel<512, true, unsigned short><<<dim3(16, 128, 2), 256, 0, stream>>>(
        Xn, Xp, Wn, Wp, Pn, Pp, Vtn, Vtp, QKC);

    attn_kernel<<<1024, 256, 0, stream>>>(Pn, Pp, Vtn, Vtp, Hn, Hp);

    // output: [16384,1024] x [1024,512] per stream -> fp32 d_out (node then pos)
    gemm_bt_kernel<1024, false, float><<<dim3(4, 128, 2), 256, 0, stream>>>(
        Hn, Hp, WoN, WoP, out, out + (size_t)TOK * EDIM,
        (unsigned short*)nullptr, (unsigned short*)nullptr, EDIM);
}

// Round 8
// 373.525 us; speedup vs baseline: 1.1110x; 1.1110x over previous
//
#include <hip/hip_runtime.h>
#include <hip/hip_bf16.h>
#include <stdint.h>

typedef __attribute__((ext_vector_type(8))) short short8;
typedef __attribute__((ext_vector_type(4))) short short4_t;
typedef __attribute__((ext_vector_type(4))) float f32x4;
typedef __attribute__((ext_vector_type(16))) float f32x16;
typedef __attribute__((ext_vector_type(4))) unsigned uint4v;

#define DEVFN static __device__ __forceinline__

constexpr int BATCH = 16;
constexpr int GRAPH = 1024;
constexpr int IDIM  = 512;
constexpr int EDIM  = 512;
constexpr int NH    = 8;
constexpr int KD    = 64;
constexpr int TOK   = BATCH * GRAPH;   // 16384
constexpr int QKC   = 1024;            // proj row width (Q|K)
constexpr int HC    = 1024;            // heads row width (8 heads * 128)
constexpr float SMSCALE = 0.125f * 1.44269504088896340736f; // 1/sqrt(64) * log2(e)

DEVFN unsigned short f2bf(float x) {
    union { float f; unsigned u; } v; v.f = x;
    unsigned r = v.u + 0x7fffu + ((v.u >> 16) & 1u);
    return (unsigned short)(r >> 16);
}

// packed f32x2 -> bf16x2 (low = a, high = b)
DEVFN unsigned cvtpk(float a, float b) {
    unsigned r;
    asm("v_cvt_pk_bf16_f32 %0, %1, %2" : "=v"(r) : "v"(a), "v"(b));
    return r;
}

// v_permlane32_swap_b32: x' = {x[0:31], y[0:31]}, y' = {x[32:63], y[32:63]}
DEVFN void plswap(unsigned &x, unsigned &y) {
    asm("v_permlane32_swap_b32 %0, %1" : "+v"(x), "+v"(y));
}

DEVFN void load16(const void* g, void* l) {
    __builtin_amdgcn_global_load_lds(
        (const __attribute__((address_space(1))) void*)g,
        (__attribute__((address_space(3))) void*)l, 16, 0, 0);
}

// ---------------- input conversion: fp32 -> bf16 (both streams) -------------
__global__ __launch_bounds__(256) void cvt_x_kernel(const float4* __restrict__ x0,
                                                    const float4* __restrict__ x1,
                                                    short4_t* __restrict__ y0,
                                                    short4_t* __restrict__ y1) {
    const float4* x = blockIdx.y ? x1 : x0;
    short4_t*     y = blockIdx.y ? y1 : y0;
    const int i = blockIdx.x * 256 + threadIdx.x;
    const float4 v = x[i];
    short4_t o;
    o[0] = (short)f2bf(v.x); o[1] = (short)f2bf(v.y);
    o[2] = (short)f2bf(v.z); o[3] = (short)f2bf(v.w);
    y[i] = o;
}

// ---------------- weight packing: LDS-tiled 64x64 transpose -----------------
__global__ __launch_bounds__(256)
void pack_w_kernel(const float* __restrict__ Wqn, const float* __restrict__ Wkn,
                   const float* __restrict__ Wvn,
                   const float* __restrict__ Wqp, const float* __restrict__ Wkp,
                   const float* __restrict__ Wvp,
                   const float* __restrict__ Won, const float* __restrict__ Wop,
                   unsigned short* __restrict__ Wn, unsigned short* __restrict__ Wp2,
                   unsigned short* __restrict__ WoN, unsigned short* __restrict__ WoP)
{
    __shared__ float T[64][65];
    const int bid = blockIdx.x, tid = threadIdx.x;

    const float* src; unsigned short* dst;
    int sld, dld; size_t sbase, dbase;
    float scale = 1.f;

    if (bid < 512) {                       // QKV: 2 streams x 256 tiles
        const int st = bid >> 8, t = bid & 255;
        const int tr = t >> 3, tc = t & 7;
        dst = st ? Wp2 : Wn;
        int head;
        if (tr < 8)       { src = st ? Wqp : Wqn; head = tr;      scale = SMSCALE; }
        else if (tr < 16) { src = st ? Wkp : Wkn; head = tr - 8; }
        else              { src = st ? Wvp : Wvn; head = tr - 16; }
        sld = 64; dld = 512;
        sbase = (size_t)(head * 512 + tc * 64) * 64;
        dbase = (size_t)(tr * 64) * 512 + tc * 64;
    } else {                               // W_out: 2 streams x 128 tiles
        const int b2 = bid - 512;
        const int st = b2 >> 7, t = b2 & 127;
        const int tr = t >> 4, tc = t & 15;
        src = st ? Wop : Won;
        dst = st ? WoP : WoN;
        sld = 512; dld = 1024;
        sbase = (size_t)(tc * 64) * 512 + tr * 64;
        dbase = (size_t)(tr * 64) * 1024 + tc * 64;
    }

    {
        const int j = tid & 63, i0 = tid >> 6;
        #pragma unroll
        for (int p = 0; p < 16; ++p) {
            const int i = p * 4 + i0;
            T[i][j] = src[sbase + (size_t)i * sld + j];
        }
    }
    __syncthreads();
    {
        const int i = tid & 63, j0 = tid >> 6;
        #pragma unroll
        for (int p = 0; p < 16; ++p) {
            const int j = p * 4 + j0;
            dst[dbase + (size_t)j * dld + i] = f2bf(T[i][j] * scale);
        }
    }
}

// ---------------- GEMM 256x256 tile, BK=64, 8 waves, counted-vmcnt pipeline --
// C[M][N] = A[M][K] * Bt[N][K]^T, bf16 MFMA 16x16x32, f32 acc.
// Double-buffered LDS (128 KB); next tile's global_load_lds stay IN FLIGHT
// across this tile's MFMA phase: s_waitcnt vmcnt(8) (in-order retire => tile t
// landed) + raw s_barrier, never draining to 0 in the main loop.
// Grid: (n_tiles, m_tiles, 2streams); gridX=8 on proj => XCD = n-panel.
// VSPLIT: n0 >= 1024 tiles write bf16 transposed into Vt[n-1024][m].
template<int K, bool VSPLIT, typename OutT>
__global__ __launch_bounds__(512, 2)
void gemm256_kernel(const unsigned short* __restrict__ A0, const unsigned short* __restrict__ A1,
                    const unsigned short* __restrict__ B0, const unsigned short* __restrict__ B1,
                    OutT* __restrict__ C0, OutT* __restrict__ C1,
                    unsigned short* __restrict__ V0, unsigned short* __restrict__ V1,
                    int ldc)
{
    __shared__ __align__(16) unsigned short smem[2][2][256 * 64];  // 128 KB
    const unsigned short* A  = blockIdx.z ? A1 : A0;
    const unsigned short* Bt = blockIdx.z ? B1 : B0;

    const int tid = threadIdx.x, lane = tid & 63;
    const int wave = tid >> 6;
    const int g = lane >> 4, ln = lane & 15;
    const int wm = wave >> 2, wn = wave & 3;         // 2(M) x 4(N) wave grid
    const int n0 = blockIdx.x * 256, m0 = blockIdx.y * 256;

    // hoisted staging pointers: chunk c = j*512+tid of the 256x64 tile
    const char* ap[4]; const char* bp[4];
    #pragma unroll
    for (int j = 0; j < 4; ++j) {
        const int c = j * 512 + tid;
        const int row = c >> 3;
        const int colg = (c & 7) ^ (row & 7);        // pre-swizzled source
        ap[j] = (const char*)(A  + (size_t)(m0 + row) * K + colg * 8);
        bp[j] = (const char*)(Bt + (size_t)(n0 + row) * K + colg * 8);
    }
    auto stage = [&](int t, int bb) {
        #pragma unroll
        for (int j = 0; j < 4; ++j) {
            const int c = j * 512 + tid;
            load16(ap[j] + t * 128, (char*)smem[bb][0] + c * 16);
            load16(bp[j] + t * 128, (char*)smem[bb][1] + c * 16);
        }
    };

    f32x4 acc[8][4] = {};                            // wave output 128(M) x 64(N)
    constexpr int NT = K / 64;

    stage(0, 0);
    for (int t = 0; t < NT; ++t) {
        const int bb = t & 1;
        if (t + 1 < NT) {
            stage(t + 1, bb ^ 1);                    // 8 more loads in flight
            asm volatile("s_waitcnt vmcnt(8)" ::: "memory");   // tile t landed
        } else {
            asm volatile("s_waitcnt vmcnt(0)" ::: "memory");
        }
        __builtin_amdgcn_s_barrier();                // all waves' slices landed

        const char* As = (const char*)smem[bb][0];
        const char* Bs = (const char*)smem[bb][1];
        short8 bfr[4][2];
        #pragma unroll
        for (int ni = 0; ni < 4; ++ni) {
            const int rb = wn * 64 + ni * 16 + ln;
            bfr[ni][0] = *(const short8*)(Bs + rb * 128 + ((g ^ (rb & 7)) * 16));
            bfr[ni][1] = *(const short8*)(Bs + rb * 128 + (((4 + g) ^ (rb & 7)) * 16));
        }
        __builtin_amdgcn_s_setprio(1);
        #pragma unroll
        for (int mi = 0; mi < 8; ++mi) {
            const int ra = wm * 128 + mi * 16 + ln;
            const short8 a0 = *(const short8*)(As + ra * 128 + ((g ^ (ra & 7)) * 16));
            const short8 a1 = *(const short8*)(As + ra * 128 + (((4 + g) ^ (ra & 7)) * 16));
            #pragma unroll
            for (int ni = 0; ni < 4; ++ni) {
                acc[mi][ni] = __builtin_amdgcn_mfma_f32_16x16x32_bf16(a0, bfr[ni][0], acc[mi][ni], 0, 0, 0);
                acc[mi][ni] = __builtin_amdgcn_mfma_f32_16x16x32_bf16(a1, bfr[ni][1], acc[mi][ni], 0, 0, 0);
            }
        }
        __builtin_amdgcn_s_setprio(0);
        __builtin_amdgcn_s_barrier();                // reads done: buf reusable
    }

    if constexpr (!VSPLIT) {
        // fp32 direct store: 16 lanes x 4B = 64B runs
        OutT* C = blockIdx.z ? C1 : C0;
        #pragma unroll
        for (int mi = 0; mi < 8; ++mi)
            #pragma unroll
            for (int ni = 0; ni < 4; ++ni)
                #pragma unroll
                for (int r = 0; r < 4; ++r) {
                    const size_t m = (size_t)(m0 + wm * 128 + mi * 16 + g * 4 + r);
                    const size_t n = (size_t)(n0 + wn * 64 + ni * 16 + ln);
                    C[m * ldc + n] = acc[mi][ni][r];
                }
    } else if (n0 < 1024) {
        // Q|K: bf16 direct scalar (L2-absorbed; bounce measured neutral r7)
        unsigned short* C = (unsigned short*)(blockIdx.z ? C1 : C0);
        #pragma unroll
        for (int mi = 0; mi < 8; ++mi)
            #pragma unroll
            for (int ni = 0; ni < 4; ++ni)
                #pragma unroll
                for (int r = 0; r < 4; ++r) {
                    const size_t m = (size_t)(m0 + wm * 128 + mi * 16 + g * 4 + r);
                    const size_t n = (size_t)(n0 + wn * 64 + ni * 16 + ln);
                    C[m * ldc + n] = f2bf(acc[mi][ni][r]);
                }
    } else {
        // V: transpose via LDS bounce (8B ds_writes along m), 2 m-half passes,
        // then 256B-coalesced row writes into Vt[n][m].
        unsigned short* Vt = blockIdx.z ? V1 : V0;
        unsigned short* Ts = &smem[0][0][0];         // [256][136] shorts = 68 KB
        #pragma unroll
        for (int mh = 0; mh < 2; ++mh) {
            if (wm == mh) {
                #pragma unroll
                for (int mi = 0; mi < 8; ++mi) {
                    const int mloc = mi * 16 + g * 4;
                    #pragma unroll
                    for (int ni = 0; ni < 4; ++ni) {
                        const int nl = wn * 64 + ni * 16 + ln;
                        uint2 w;
                        w.x = cvtpk(acc[mi][ni][0], acc[mi][ni][1]);
                        w.y = cvtpk(acc[mi][ni][2], acc[mi][ni][3]);
                        *(uint2*)(Ts + nl * 136 + mloc) = w;
                    }
                }
            }
            __syncthreads();
            #pragma unroll
            for (int it = 0; it < 8; ++it) {
                const int c = it * 512 + tid;
                const int row = c >> 4, gr = c & 15;
                *(short8*)(Vt + (size_t)(n0 - 1024 + row) * TOK + m0 + mh * 128 + gr * 8) =
                    *(const short8*)(Ts + row * 136 + gr * 8);
            }
            __syncthreads();
        }
    }
}

// ---------------- fused flash attention, 32x32x16 MFMA, 64 q per wave -------
// (unchanged from round 6: 124 µs, MfmaUtil 36.5%, HBM 14%)
__global__ __launch_bounds__(256, 2)
void attn_kernel(const unsigned short* __restrict__ projn,
                 const unsigned short* __restrict__ projp,
                 const unsigned short* __restrict__ Vtn,
                 const unsigned short* __restrict__ Vtp,
                 unsigned short* __restrict__ headsn,
                 unsigned short* __restrict__ headsp)
{
    __shared__ unsigned short Kl[2][64 * 64];     // 2 x  8KB  [key][d]
    __shared__ unsigned short Vl[2][128 * 64];    // 2 x 16KB  [v][key]

    const int bid  = blockIdx.x;
    const int slot = bid >> 3;
    const int g    = (bid & 7) * 32 + (slot >> 2);
    const int qt   = slot & 3;
    const int a    = (g & 15) >> 3, h = g & 7;
    const int b    = g >> 4;

    const int tid = threadIdx.x, wave = tid >> 6, lane = tid & 63;
    const int q = lane & 31, hi = lane >> 5;

    const unsigned short* proj = a ? projp : projn;
    const int tok0 = b * GRAPH;
    const size_t qrow0 = (size_t)(tok0 + qt * 256 + wave * 64 + q);  // qi adds 32
    const int qc  = h * KD;
    const int kc  = IDIM + h * KD;
    const int vr0 = (a * NH + h) * KD;

    short8 qf[2][4];
    #pragma unroll
    for (int qi = 0; qi < 2; ++qi)
        #pragma unroll
        for (int ds = 0; ds < 4; ++ds)
            qf[qi][ds] = *(const short8*)(proj + (qrow0 + qi * 32) * QKC + qc + ds * 16 + hi * 8);

    const char* kap[2]; int kds[2];
    #pragma unroll
    for (int j = 0; j < 2; ++j) {
        const int c = (wave * 2 + j) * 64 + lane;
        const int row = c >> 3;
        const int col = ((c & 7) ^ (row & 7)) * 8;
        kap[j] = (const char*)(proj + (size_t)(tok0 + row) * QKC + kc + col);
        kds[j] = c * 16;
    }
    const char* vap[4]; int vds[4];
    #pragma unroll
    for (int j = 0; j < 4; ++j) {
        const int c = (wave * 4 + j) * 64 + lane;
        const int row = c >> 3;
        const int col = ((c & 7) ^ (row & 7)) * 8;
        const unsigned short* base = (row < 64)
            ? (Vtn + (size_t)(vr0 + row) * TOK)
            : (Vtp + (size_t)(vr0 + row - 64) * TOK);
        vap[j] = (const char*)(base + tok0 + col);
        vds[j] = c * 16;
    }

    auto stage = [&](int bb) {
        #pragma unroll
        for (int j = 0; j < 2; ++j) { load16(kap[j], (char*)Kl[bb] + kds[j]); kap[j] += (size_t)64 * QKC * 2; }
        #pragma unroll
        for (int j = 0; j < 4; ++j) { load16(vap[j], (char*)Vl[bb] + vds[j]); vap[j] += 64 * 2; }
    };

    f32x16 oacc[2][4] = {};
    float l_run[2] = {0.f, 0.f};

    stage(0);
    __syncthreads();

    for (int kt = 0; kt < 16; ++kt) {
        const int bb = kt & 1;
        if (kt < 15) stage(bb ^ 1);

        short8 pfrag[2][4];
        #pragma unroll
        for (int kb = 0; kb < 2; ++kb) {
            f32x16 s0 = {}, s1 = {};
            __builtin_amdgcn_s_setprio(1);
            #pragma unroll
            for (int ds = 0; ds < 4; ++ds) {
                const int row = kb * 32 + q;
                const short8 kf = *(const short8*)((const char*)Kl[bb] + row * 128 + (((ds * 2 + hi) ^ (row & 7)) * 16));
                s0 = __builtin_amdgcn_mfma_f32_32x32x16_bf16(kf, qf[0][ds], s0, 0, 0, 0);
                s1 = __builtin_amdgcn_mfma_f32_32x32x16_bf16(kf, qf[1][ds], s1, 0, 0, 0);
            }
            __builtin_amdgcn_s_setprio(0);

            float ps0 = 0.f, ps1 = 0.f;
            #pragma unroll
            for (int r = 0; r < 16; ++r) {
                const float p0 = __builtin_amdgcn_exp2f(s0[r]); s0[r] = p0; ps0 += p0;
                const float p1 = __builtin_amdgcn_exp2f(s1[r]); s1[r] = p1; ps1 += p1;
            }
            l_run[0] += ps0; l_run[1] += ps1;

            #pragma unroll
            for (int sh = 0; sh < 2; ++sh) {
                const int s = kb * 2 + sh, o = 8 * sh;
                {
                    unsigned A0 = cvtpk(s0[o + 0], s0[o + 1]);
                    unsigned A1 = cvtpk(s0[o + 2], s0[o + 3]);
                    unsigned B0 = cvtpk(s0[o + 4], s0[o + 5]);
                    unsigned B1 = cvtpk(s0[o + 6], s0[o + 7]);
                    plswap(A0, B0); plswap(A1, B1);
                    uint4v pw; pw[0] = A0; pw[1] = A1; pw[2] = B0; pw[3] = B1;
                    pfrag[0][s] = __builtin_bit_cast(short8, pw);
                }
                {
                    unsigned A0 = cvtpk(s1[o + 0], s1[o + 1]);
                    unsigned A1 = cvtpk(s1[o + 2], s1[o + 3]);
                    unsigned B0 = cvtpk(s1[o + 4], s1[o + 5]);
                    unsigned B1 = cvtpk(s1[o + 6], s1[o + 7]);
                    plswap(A0, B0); plswap(A1, B1);
                    uint4v pw; pw[0] = A0; pw[1] = A1; pw[2] = B0; pw[3] = B1;
                    pfrag[1][s] = __builtin_bit_cast(short8, pw);
                }
            }
        }

        __builtin_amdgcn_s_setprio(1);
        #pragma unroll
        for (int s = 0; s < 4; ++s) {
            #pragma unroll
            for (int vb = 0; vb < 4; ++vb) {
                const int row = vb * 32 + q;
                const short8 vf = *(const short8*)((const char*)Vl[bb] + row * 128 + (((s * 2 + hi) ^ (row & 7)) * 16));
                oacc[0][vb] = __builtin_amdgcn_mfma_f32_32x32x16_bf16(vf, pfrag[0][s], oacc[0][vb], 0, 0, 0);
                oacc[1][vb] = __builtin_amdgcn_mfma_f32_32x32x16_bf16(vf, pfrag[1][s], oacc[1][vb], 0, 0, 0);
            }
        }
        __builtin_amdgcn_s_setprio(0);
        __syncthreads();
    }

    #pragma unroll
    for (int qi = 0; qi < 2; ++qi) {
        l_run[qi] += __shfl_xor(l_run[qi], 32);
        const float inv = 1.0f / l_run[qi];
        const size_t qrow = qrow0 + qi * 32;
        #pragma unroll
        for (int vb = 0; vb < 4; ++vb) {
            unsigned short* heads = (vb < 2) ? headsn : headsp;
            const int colbase = h * 128 + a * 64 + (vb & 1) * 32;
            #pragma unroll
            for (int w = 0; w < 8; ++w) {
                const unsigned pk = cvtpk(oacc[qi][vb][2 * w] * inv, oacc[qi][vb][2 * w + 1] * inv);
                const int v = ((2 * w) & 3) + 8 * (w >> 1) + 4 * hi;
                *(unsigned*)(heads + qrow * HC + colbase + v) = pk;
            }
        }
    }
}

// ---------------- host launch ----------------
extern "C" void kernel_launch(void* const* d_in, const int* in_sizes, int n_in,
                              void* d_out, int out_size, void* d_ws, size_t ws_size,
                              hipStream_t stream)
{
    const float* hn  = (const float*)d_in[0];
    const float* hp  = (const float*)d_in[1];
    const float* Wqn = (const float*)d_in[2];
    const float* Wqp = (const float*)d_in[3];
    const float* Wkn = (const float*)d_in[4];
    const float* Wkp = (const float*)d_in[5];
    const float* Wvn = (const float*)d_in[6];
    const float* Wvp = (const float*)d_in[7];
    const float* Won = (const float*)d_in[8];
    const float* Wop = (const float*)d_in[9];
    float* out = (float*)d_out;

    char* ws = (char*)d_ws;
    size_t off = 0;
    auto take = [&](size_t nbytes) -> char* {
        char* p = ws + off;
        off += (nbytes + 255) & ~(size_t)255;
        return p;
    };
    unsigned short* Xn  = (unsigned short*)take((size_t)TOK * IDIM * 2);
    unsigned short* Xp  = (unsigned short*)take((size_t)TOK * IDIM * 2);
    unsigned short* Wn  = (unsigned short*)take((size_t)2048 * 512 * 2);
    unsigned short* Wp  = (unsigned short*)take((size_t)2048 * 512 * 2);
    unsigned short* WoN = (unsigned short*)take((size_t)512 * 1024 * 2);
    unsigned short* WoP = (unsigned short*)take((size_t)512 * 1024 * 2);
    unsigned short* Pn  = (unsigned short*)take((size_t)TOK * QKC * 2);
    unsigned short* Pp  = (unsigned short*)take((size_t)TOK * QKC * 2);
    unsigned short* Vtn = (unsigned short*)take((size_t)1024 * TOK * 2);
    unsigned short* Vtp = (unsigned short*)take((size_t)1024 * TOK * 2);
    unsigned short* Hn  = (unsigned short*)take((size_t)TOK * HC * 2);
    unsigned short* Hp  = (unsigned short*)take((size_t)TOK * HC * 2);

    cvt_x_kernel<<<dim3(TOK * IDIM / 4 / 256, 2), 256, 0, stream>>>(
        (const float4*)hn, (const float4*)hp, (short4_t*)Xn, (short4_t*)Xp);
    pack_w_kernel<<<768, 256, 0, stream>>>(
        Wqn, Wkn, Wvn, Wqp, Wkp, Wvp, Won, Wop, Wn, Wp, WoN, WoP);

    // projections: [16384,512] x [512,2048] per stream; gridX = 8 n-panels (XCD pin)
    gemm256_kernel<512, true, unsigned short><<<dim3(8, 64, 2), 512, 0, stream>>>(
        Xn, Xp, Wn, Wp, Pn, Pp, Vtn, Vtp, QKC);

    attn_kernel<<<1024, 256, 0, stream>>>(Pn, Pp, Vtn, Vtp, Hn, Hp);

    // output: [16384,1024] x [1024,512] per stream -> fp32 d_out (node then pos)
    gemm256_kernel<1024, false, float><<<dim3(2, 64, 2), 512, 0, stream>>>(
        Hn, Hp, WoN, WoP, out, out + (size_t)TOK * EDIM,
        (unsigned short*)nullptr, (unsigned short*)nullptr, EDIM);
}